// Round 3
// baseline (1187.025 us; speedup 1.0000x reference)
//
#include <hip/hip_runtime.h>

#define NN 100000   // real nodes
#define NP 100096   // padded to 782*128
#define NE 600000   // edges
#define CC 128      // channels

typedef __attribute__((ext_vector_type(4))) float f4;
typedef __attribute__((ext_vector_type(2))) float f2;

// ---------------- graph preprocessing ----------------

__global__ void k_deg(const int* __restrict__ col, int* __restrict__ deg) {
  int e = blockIdx.x * 256 + threadIdx.x;
  if (e < NE) atomicAdd(&deg[col[e]], 1);
}

__global__ void k_dis(const int* __restrict__ deg, float* __restrict__ dis) {
  int n = blockIdx.x * 256 + threadIdx.x;
  if (n >= NP) return;
  int d = (n < NN) ? deg[n] : 0;
  dis[n] = (d > 0) ? rsqrtf((float)d) : 0.0f;
}

__global__ void k_scan1(const int* __restrict__ deg, int* __restrict__ rowptr,
                        int* __restrict__ bsum) {
  __shared__ int s[1024];
  int t = threadIdx.x;
  int i = blockIdx.x * 1024 + t;
  int v = (i < NN) ? deg[i] : 0;
  s[t] = v;
  __syncthreads();
  #pragma unroll
  for (int off = 1; off < 1024; off <<= 1) {
    int tv = (t >= off) ? s[t - off] : 0;
    __syncthreads();
    s[t] += tv;
    __syncthreads();
  }
  if (i < NN) rowptr[i] = s[t] - v;           // exclusive
  if (t == 1023) bsum[blockIdx.x] = s[1023];
}

__global__ void k_scan2(const int* __restrict__ bsum, int* __restrict__ bsum2) {
  __shared__ int s[128];
  int t = threadIdx.x;
  int v = (t < 98) ? bsum[t] : 0;
  s[t] = v;
  __syncthreads();
  #pragma unroll
  for (int off = 1; off < 128; off <<= 1) {
    int tv = (t >= off) ? s[t - off] : 0;
    __syncthreads();
    s[t] += tv;
    __syncthreads();
  }
  bsum2[t] = s[t] - v;                        // exclusive
}

__global__ void k_scan3(int* __restrict__ rowptr, const int* __restrict__ bsum2) {
  int i = blockIdx.x * 1024 + threadIdx.x;
  if (i < NN) rowptr[i] += bsum2[blockIdx.x];
}

__global__ void k_fill(const int* __restrict__ row, const int* __restrict__ col,
                       const float* __restrict__ dis, const int* __restrict__ rowptr,
                       int* __restrict__ cnt, int* __restrict__ csr_src,
                       float* __restrict__ csr_w) {
  int e = blockIdx.x * 256 + threadIdx.x;
  if (e >= NE) return;
  int c = col[e], r = row[e];
  int pos = rowptr[c] + atomicAdd(&cnt[c], 1);
  csr_src[pos] = r;
  csr_w[pos] = dis[r] * dis[c];
}

// ---------------- lin0: h = relu(x @ W0 + b0), x is [N,6] ----------------

__global__ void k_lin0(const float* __restrict__ x, const float* __restrict__ W0,
                       const float* __restrict__ b0, float* __restrict__ h) {
  int idx = blockIdx.x * 256 + threadIdx.x;   // n*128 + c
  int n = idx >> 7, c = idx & 127;
  if (n >= NP) return;
  float v = 0.0f;
  if (n < NN) {
    v = b0[c];
    #pragma unroll
    for (int f = 0; f < 6; ++f) v = fmaf(x[n * 6 + f], W0[f * CC + c], v);
    v = fmaxf(v, 0.0f);
  }
  h[idx] = v;
}

// ---------------- propagation: xout[n] = sum_{e: col=n} w_e * xin[src_e] ----------------
// one 64-lane wave per node, each lane owns 2 channels (float2 = 512B/wave coalesced)

__global__ void k_prop(const int* __restrict__ rowptr, const int* __restrict__ deg,
                       const int* __restrict__ csr_src, const float* __restrict__ csr_w,
                       const float* __restrict__ xin, float* __restrict__ xout) {
  int gid = blockIdx.x * 256 + threadIdx.x;
  int wid = gid >> 6;            // node
  int lane = gid & 63;
  if (wid >= NP) return;
  f2 acc = {0.0f, 0.0f};
  if (wid < NN) {
    int start = rowptr[wid];
    int end = start + deg[wid];
    for (int j = start; j < end; ++j) {
      int s = csr_src[j];
      float w = csr_w[j];
      f2 v = *reinterpret_cast<const f2*>(&xin[(long)s * CC + lane * 2]);
      acc += v * w;
    }
  }
  *reinterpret_cast<f2*>(&xout[(long)wid * CC + lane * 2]) = acc;
}

// ---------------- GEMM: Y = [Acc +] X @ W [+ bias, relu] ; X:[NP,128] W:[128,128] ----------------
// 256 thr, 128 rows/block. X tile in 64KB LDS (XOR-swizzled), W via L1/L2.
// thread (tr=t>>4, tc=t&15) owns rows {tr+16i} x cols {tc*4+j, 64+tc*4+j}

template<bool ACC, bool BR>
__global__ __launch_bounds__(256, 2) void k_gemm(const float* __restrict__ X,
                                                 const float* __restrict__ W,
                                                 const float* __restrict__ Acc,
                                                 const float* __restrict__ bias,
                                                 float* __restrict__ Y) {
  __shared__ float hs[128 * 128];             // 64 KB, swizzled
  int t = threadIdx.x;
  long row0 = (long)blockIdx.x * 128;

  for (int idx = t; idx < 128 * 32; idx += 256) {
    int r = idx >> 5, c4 = idx & 31;
    f4 v = *reinterpret_cast<const f4*>(&X[(row0 + r) * CC + c4 * 4]);
    int fi = r * 128 + ((c4 * 4) ^ ((r & 7) << 2));   // 16B-granule XOR swizzle
    *reinterpret_cast<f4*>(&hs[fi]) = v;
  }
  __syncthreads();

  int tc = t & 15, tr = t >> 4;
  int xr = (tr & 7) << 2;                     // swizzle constant for this thread's rows
  float acc[8][8];
  #pragma unroll
  for (int i = 0; i < 8; ++i)
    #pragma unroll
    for (int j = 0; j < 8; ++j) acc[i][j] = 0.0f;

  for (int k0 = 0; k0 < 128; k0 += 4) {
    f4 a[8];
    #pragma unroll
    for (int i = 0; i < 8; ++i)
      a[i] = *reinterpret_cast<const f4*>(&hs[(tr + 16 * i) * 128 + (k0 ^ xr)]);
    f4 b0v[4], b1v[4];
    #pragma unroll
    for (int kk = 0; kk < 4; ++kk) {
      b0v[kk] = *reinterpret_cast<const f4*>(&W[(k0 + kk) * CC + tc * 4]);
      b1v[kk] = *reinterpret_cast<const f4*>(&W[(k0 + kk) * CC + 64 + tc * 4]);
    }
    #pragma unroll
    for (int kk = 0; kk < 4; ++kk)
      #pragma unroll
      for (int i = 0; i < 8; ++i) {
        float av = a[i][kk];
        #pragma unroll
        for (int j = 0; j < 4; ++j) {
          acc[i][j]     = fmaf(av, b0v[kk][j], acc[i][j]);
          acc[i][j + 4] = fmaf(av, b1v[kk][j], acc[i][j + 4]);
        }
      }
  }

  f4 ba = {0,0,0,0}, bb = {0,0,0,0};
  if (BR) {
    ba = *reinterpret_cast<const f4*>(&bias[tc * 4]);
    bb = *reinterpret_cast<const f4*>(&bias[64 + tc * 4]);
  }
  #pragma unroll
  for (int i = 0; i < 8; ++i) {
    long r = row0 + tr + 16 * i;
    f4 v0, v1;
    #pragma unroll
    for (int j = 0; j < 4; ++j) { v0[j] = acc[i][j]; v1[j] = acc[i][j + 4]; }
    if (ACC) {
      v0 += *reinterpret_cast<const f4*>(&Acc[r * CC + tc * 4]);
      v1 += *reinterpret_cast<const f4*>(&Acc[r * CC + 64 + tc * 4]);
    }
    if (BR) {
      v0 += ba; v1 += bb;
      #pragma unroll
      for (int j = 0; j < 4; ++j) { v0[j] = fmaxf(v0[j], 0.0f); v1[j] = fmaxf(v1[j], 0.0f); }
    }
    *reinterpret_cast<f4*>(&Y[r * CC + tc * 4]) = v0;
    *reinterpret_cast<f4*>(&Y[r * CC + 64 + tc * 4]) = v1;
  }
}

// ---------------- head: out = relu(h @ W1 + b1), one wave per node ----------------

__global__ void k_head(const float* __restrict__ h, const float* __restrict__ W1,
                       const float* __restrict__ b1, float* __restrict__ out) {
  int gid = blockIdx.x * 256 + threadIdx.x;
  int wid = gid >> 6, lane = gid & 63;
  if (wid >= NN) return;
  const float* hp = &h[(long)wid * CC];
  float v = hp[lane] * W1[lane] + hp[lane + 64] * W1[lane + 64];
  #pragma unroll
  for (int o = 32; o > 0; o >>= 1) v += __shfl_down(v, o);
  if (lane == 0) out[wid] = fmaxf(v + b1[0], 0.0f);
}

// ---------------- launch ----------------

extern "C" void kernel_launch(void* const* d_in, const int* in_sizes, int n_in,
                              void* d_out, int out_size, void* d_ws, size_t ws_size,
                              hipStream_t stream) {
  const float* x     = (const float*)d_in[0];
  const int*   ei    = (const int*)d_in[1];
  const float* W0    = (const float*)d_in[2];
  const float* b0    = (const float*)d_in[3];
  const float* W_tag = (const float*)d_in[4];
  const float* b_tag = (const float*)d_in[5];
  const float* W_mlp = (const float*)d_in[6];
  const float* b_mlp = (const float*)d_in[7];
  const float* W1    = (const float*)d_in[8];
  const float* b1    = (const float*)d_in[9];
  const int* row = ei;          // edge_index[0] = source
  const int* col = ei + NE;     // edge_index[1] = target

  char* p = (char*)d_ws;
  auto carve = [&](size_t bytes) { void* r = (void*)p; p += (bytes + 255) & ~(size_t)255; return r; };
  float* h      = (float*)carve((size_t)NP * CC * 4);
  float* xa     = (float*)carve((size_t)NP * CC * 4);
  float* xb     = (float*)carve((size_t)NP * CC * 4);
  float* outb   = (float*)carve((size_t)NP * CC * 4);
  float* dis    = (float*)carve((size_t)NP * 4);
  int*   deg    = (int*)carve((size_t)NP * 4);
  int*   rowptr = (int*)carve((size_t)NN * 4);
  int*   cnt    = (int*)carve((size_t)NN * 4);
  int*   bsum   = (int*)carve(512);
  int*   bsum2  = (int*)carve(512);
  int*   csr_src= (int*)carve((size_t)NE * 4);
  float* csr_w  = (float*)carve((size_t)NE * 4);

  hipMemsetAsync(deg, 0, (size_t)NP * 4, stream);
  hipMemsetAsync(cnt, 0, (size_t)NN * 4, stream);

  k_deg<<<(NE + 255) / 256, 256, 0, stream>>>(col, deg);
  k_dis<<<(NP + 255) / 256, 256, 0, stream>>>(deg, dis);
  k_scan1<<<98, 1024, 0, stream>>>(deg, rowptr, bsum);
  k_scan2<<<1, 128, 0, stream>>>(bsum, bsum2);
  k_scan3<<<98, 1024, 0, stream>>>(rowptr, bsum2);
  k_fill<<<(NE + 255) / 256, 256, 0, stream>>>(row, col, dis, rowptr, cnt, csr_src, csr_w);

  k_lin0<<<NP * CC / 256, 256, 0, stream>>>(x, W0, b0, h);

  const int GB = NP / 128;             // 782 gemm blocks
  const int PB = NP * 64 / 256;        // prop blocks (4 waves each)

  for (int g = 0; g < 2; ++g) {
    const float* Wg = W_tag + (size_t)g * 4 * CC * CC;
    const float* bg = b_tag + (size_t)g * CC;
    k_gemm<false, false><<<GB, 256, 0, stream>>>(h, Wg, nullptr, nullptr, outb);
    k_prop<<<PB, 256, 0, stream>>>(rowptr, deg, csr_src, csr_w, h, xa);
    k_gemm<true, false><<<GB, 256, 0, stream>>>(xa, Wg + CC * CC, outb, nullptr, outb);
    k_prop<<<PB, 256, 0, stream>>>(rowptr, deg, csr_src, csr_w, xa, xb);
    k_gemm<true, false><<<GB, 256, 0, stream>>>(xb, Wg + 2 * CC * CC, outb, nullptr, outb);
    k_prop<<<PB, 256, 0, stream>>>(rowptr, deg, csr_src, csr_w, xb, xa);
    k_gemm<true, true><<<GB, 256, 0, stream>>>(xa, Wg + 3 * CC * CC, outb, bg, h);
  }

  k_gemm<false, true><<<GB, 256, 0, stream>>>(h, W_mlp, nullptr, b_mlp, xa);
  k_gemm<false, true><<<GB, 256, 0, stream>>>(xa, W_mlp + CC * CC, nullptr, b_mlp + CC, h);

  k_head<<<(NN * 64) / 256, 256, 0, stream>>>(h, W1, b1, (float*)d_out);
}

// Round 8
// 489.056 us; speedup vs baseline: 2.4272x; 2.4272x over previous
//
#include <hip/hip_runtime.h>

#define NN 100000   // real nodes
#define NP 100096   // padded to 782*128
#define NE 600000   // edges
#define CC 128      // channels

typedef __attribute__((ext_vector_type(4))) float f32x4;
typedef _Float16 h8 __attribute__((ext_vector_type(8)));
typedef _Float16 h2 __attribute__((ext_vector_type(2)));

// ---------------- graph preprocessing ----------------

__global__ void k_deg(const int* __restrict__ col, int* __restrict__ deg) {
  int e = blockIdx.x * 256 + threadIdx.x;
  if (e < NE) atomicAdd(&deg[col[e]], 1);
}

__global__ void k_dis(const int* __restrict__ deg, float* __restrict__ dis) {
  int n = blockIdx.x * 256 + threadIdx.x;
  if (n >= NP) return;
  int d = (n < NN) ? deg[n] : 0;
  dis[n] = (d > 0) ? rsqrtf((float)d) : 0.0f;
}

__global__ void k_scan1(const int* __restrict__ deg, int* __restrict__ rowptr,
                        int* __restrict__ bsum) {
  __shared__ int s[1024];
  int t = threadIdx.x;
  int i = blockIdx.x * 1024 + t;
  int v = (i < NN) ? deg[i] : 0;
  s[t] = v;
  __syncthreads();
  #pragma unroll
  for (int off = 1; off < 1024; off <<= 1) {
    int tv = (t >= off) ? s[t - off] : 0;
    __syncthreads();
    s[t] += tv;
    __syncthreads();
  }
  if (i < NN) rowptr[i] = s[t] - v;           // exclusive
  if (t == 1023) bsum[blockIdx.x] = s[1023];
}

__global__ void k_scan2(const int* __restrict__ bsum, int* __restrict__ bsum2) {
  __shared__ int s[128];
  int t = threadIdx.x;
  int v = (t < 98) ? bsum[t] : 0;
  s[t] = v;
  __syncthreads();
  #pragma unroll
  for (int off = 1; off < 128; off <<= 1) {
    int tv = (t >= off) ? s[t - off] : 0;
    __syncthreads();
    s[t] += tv;
    __syncthreads();
  }
  bsum2[t] = s[t] - v;                        // exclusive
}

__global__ void k_scan3(int* __restrict__ rowptr, const int* __restrict__ bsum2) {
  int i = blockIdx.x * 1024 + threadIdx.x;
  if (i < NN) rowptr[i] += bsum2[blockIdx.x];
}

__global__ void k_fill(const int* __restrict__ row, const int* __restrict__ col,
                       const float* __restrict__ dis, const int* __restrict__ rowptr,
                       int* __restrict__ cnt, int* __restrict__ csr_src,
                       float* __restrict__ csr_w) {
  int e = blockIdx.x * 256 + threadIdx.x;
  if (e >= NE) return;
  int c = col[e], r = row[e];
  int pos = rowptr[c] + atomicAdd(&cnt[c], 1);
  csr_src[pos] = r;
  csr_w[pos] = dis[r] * dis[c];
}

// ---------------- W conversion: fp32 [K][128] -> fp16 MFMA-B-permuted ----------------
// dst[((kb*8+nb)*64+l)*8+e] = src[(kb*32+(l>>4)*8+e)*128 + nb*16+(l&15)]

__global__ void k_wconv(const float* __restrict__ src, _Float16* __restrict__ dst, int K) {
  int tid = blockIdx.x * 256 + threadIdx.x;
  if (tid >= K * 128) return;
  int e = tid & 7, l = (tid >> 3) & 63, nb = (tid >> 9) & 7, kb = tid >> 12;
  int k = kb * 32 + (l >> 4) * 8 + e;
  int c = nb * 16 + (l & 15);
  dst[tid] = (_Float16)src[k * 128 + c];
}

// ---------------- lin0: h = relu(x @ W0 + b0), x is [N,6], out fp16 ----------------

__global__ void k_lin0(const float* __restrict__ x, const float* __restrict__ W0,
                       const float* __restrict__ b0, _Float16* __restrict__ h) {
  int idx = blockIdx.x * 256 + threadIdx.x;   // n*128 + c
  int n = idx >> 7, c = idx & 127;
  if (n >= NP) return;
  float v = 0.0f;
  if (n < NN) {
    v = b0[c];
    #pragma unroll
    for (int f = 0; f < 6; ++f) v = fmaf(x[n * 6 + f], W0[f * CC + c], v);
    v = fmaxf(v, 0.0f);
  }
  h[idx] = (_Float16)v;
}

// ---------------- propagation (fp16 features, unroll-4 ILP) ----------------
// one wave per node, lane owns 2 channels (half2 = 256B/wave per neighbor)

__global__ void k_prop(const int* __restrict__ rowptr, const int* __restrict__ deg,
                       const int* __restrict__ csr_src, const float* __restrict__ csr_w,
                       const _Float16* __restrict__ xin, _Float16* __restrict__ xout) {
  int gid = blockIdx.x * 256 + threadIdx.x;
  int wid = gid >> 6;            // node
  int lane = gid & 63;
  if (wid >= NP) return;
  float a0 = 0.0f, a1 = 0.0f;
  if (wid < NN) {
    int start = rowptr[wid];
    int end = start + deg[wid];
    int j = start;
    for (; j + 4 <= end; j += 4) {             // batch 4 edges: independent gathers
      int s0 = csr_src[j], s1 = csr_src[j + 1], s2 = csr_src[j + 2], s3 = csr_src[j + 3];
      float w0 = csr_w[j], w1 = csr_w[j + 1], w2 = csr_w[j + 2], w3 = csr_w[j + 3];
      h2 v0 = *reinterpret_cast<const h2*>(&xin[s0 * CC + lane * 2]);
      h2 v1 = *reinterpret_cast<const h2*>(&xin[s1 * CC + lane * 2]);
      h2 v2 = *reinterpret_cast<const h2*>(&xin[s2 * CC + lane * 2]);
      h2 v3 = *reinterpret_cast<const h2*>(&xin[s3 * CC + lane * 2]);
      a0 += w0 * (float)v0[0] + w1 * (float)v1[0] + w2 * (float)v2[0] + w3 * (float)v3[0];
      a1 += w0 * (float)v0[1] + w1 * (float)v1[1] + w2 * (float)v2[1] + w3 * (float)v3[1];
    }
    for (; j < end; ++j) {
      int s = csr_src[j];
      float w = csr_w[j];
      h2 v = *reinterpret_cast<const h2*>(&xin[s * CC + lane * 2]);
      a0 += w * (float)v[0];
      a1 += w * (float)v[1];
    }
  }
  h2 o; o[0] = (_Float16)a0; o[1] = (_Float16)a1;
  *reinterpret_cast<h2*>(&xout[wid * CC + lane * 2]) = o;
}

// ---------------- MFMA GEMM: Y = relu?(cat(X0..X{KB-1}) @ Wp + bias), fp16 in/out ----
// block = 4 waves, 128x128 tile; wave w: rows (w&1)*64, cols (w>>1)*64 (4x4 frags of 16x16)
// A direct from global (16B/lane); B from permuted Wp (16B/lane, L1-hot). No LDS.

template<int KB, bool BR>
__global__ __launch_bounds__(256) void k_mm(const _Float16* __restrict__ X0,
                                            const _Float16* __restrict__ X1,
                                            const _Float16* __restrict__ X2,
                                            const _Float16* __restrict__ X3,
                                            const _Float16* __restrict__ Wp,
                                            const float* __restrict__ bias,
                                            _Float16* __restrict__ Y) {
  int t = threadIdx.x;
  int w = t >> 6, l = t & 63;
  int lr = l & 15, lk = l >> 4;
  int m0 = blockIdx.x * 128 + (w & 1) * 64;
  int nb0 = (w >> 1) * 4;                     // n-frag base (16 cols each)
  const _Float16* Xs[4] = {X0, X1, X2, X3};

  f32x4 acc[4][4];
  #pragma unroll
  for (int m = 0; m < 4; ++m)
    #pragma unroll
    for (int n = 0; n < 4; ++n) acc[m][n] = (f32x4){0.f, 0.f, 0.f, 0.f};

  #pragma unroll
  for (int xi = 0; xi < KB; ++xi) {           // full unroll -> Xs[xi] static
    const _Float16* __restrict__ xb = Xs[xi];
    #pragma unroll 2
    for (int kk = 0; kk < 4; ++kk) {          // K=32 steps within one 128-col buffer
      int kb = xi * 4 + kk;
      int ke = kk * 32 + lk * 8;
      h8 a[4], b[4];
      #pragma unroll
      for (int m = 0; m < 4; ++m)
        a[m] = *reinterpret_cast<const h8*>(&xb[(m0 + m * 16 + lr) * CC + ke]);
      #pragma unroll
      for (int n = 0; n < 4; ++n)
        b[n] = *reinterpret_cast<const h8*>(&Wp[((kb * 8 + nb0 + n) * 64 + l) * 8]);
      #pragma unroll
      for (int m = 0; m < 4; ++m)
        #pragma unroll
        for (int n = 0; n < 4; ++n)
          acc[m][n] = __builtin_amdgcn_mfma_f32_16x16x32_f16(a[m], b[n], acc[m][n], 0, 0, 0);
    }
  }

  // C/D layout (m89-verified): col = lane&15, row = (lane>>4)*4 + reg
  int r0 = m0 + lk * 4;
  #pragma unroll
  for (int m = 0; m < 4; ++m) {
    #pragma unroll
    for (int n = 0; n < 4; ++n) {
      int c = (nb0 + n) * 16 + lr;
      float bv = BR ? bias[c] : 0.0f;
      #pragma unroll
      for (int q = 0; q < 4; ++q) {
        float v = acc[m][n][q] + bv;
        if (BR) v = fmaxf(v, 0.0f);
        Y[(r0 + m * 16 + q) * CC + c] = (_Float16)v;
      }
    }
  }
}

// ---------------- head: out = relu(h @ W1 + b1), one wave per node ----------------

__global__ void k_head(const _Float16* __restrict__ h, const float* __restrict__ W1,
                       const float* __restrict__ b1, float* __restrict__ out) {
  int gid = blockIdx.x * 256 + threadIdx.x;
  int wid = gid >> 6, lane = gid & 63;
  if (wid >= NN) return;
  const _Float16* hp = &h[wid * CC];
  float v = (float)hp[lane] * W1[lane] + (float)hp[lane + 64] * W1[lane + 64];
  #pragma unroll
  for (int o = 32; o > 0; o >>= 1) v += __shfl_down(v, o);
  if (lane == 0) out[wid] = fmaxf(v + b1[0], 0.0f);
}

// ---------------- launch ----------------

extern "C" void kernel_launch(void* const* d_in, const int* in_sizes, int n_in,
                              void* d_out, int out_size, void* d_ws, size_t ws_size,
                              hipStream_t stream) {
  const float* x     = (const float*)d_in[0];
  const int*   ei    = (const int*)d_in[1];
  const float* W0    = (const float*)d_in[2];
  const float* b0    = (const float*)d_in[3];
  const float* W_tag = (const float*)d_in[4];
  const float* b_tag = (const float*)d_in[5];
  const float* W_mlp = (const float*)d_in[6];
  const float* b_mlp = (const float*)d_in[7];
  const float* W1    = (const float*)d_in[8];
  const float* b1    = (const float*)d_in[9];
  const int* row = ei;          // edge_index[0] = source
  const int* col = ei + NE;     // edge_index[1] = target

  char* p = (char*)d_ws;
  auto carve = [&](size_t bytes) { void* r = (void*)p; p += (bytes + 255) & ~(size_t)255; return r; };
  _Float16* hA   = (_Float16*)carve((size_t)NP * CC * 2);
  _Float16* hB   = (_Float16*)carve((size_t)NP * CC * 2);
  _Float16* x1   = (_Float16*)carve((size_t)NP * CC * 2);
  _Float16* x2   = (_Float16*)carve((size_t)NP * CC * 2);
  _Float16* x3   = (_Float16*)carve((size_t)NP * CC * 2);
  _Float16* WpT0 = (_Float16*)carve((size_t)512 * CC * 2);
  _Float16* WpT1 = (_Float16*)carve((size_t)512 * CC * 2);
  _Float16* WpM0 = (_Float16*)carve((size_t)CC * CC * 2);
  _Float16* WpM1 = (_Float16*)carve((size_t)CC * CC * 2);
  float* dis     = (float*)carve((size_t)NP * 4);
  int*   deg     = (int*)carve((size_t)NP * 4);
  int*   rowptr  = (int*)carve((size_t)NN * 4);
  int*   cnt     = (int*)carve((size_t)NN * 4);
  int*   bsum    = (int*)carve(512);
  int*   bsum2   = (int*)carve(512);
  int*   csr_src = (int*)carve((size_t)NE * 4);
  float* csr_w   = (float*)carve((size_t)NE * 4);

  hipMemsetAsync(deg, 0, (size_t)NP * 4, stream);
  hipMemsetAsync(cnt, 0, (size_t)NN * 4, stream);

  k_deg<<<(NE + 255) / 256, 256, 0, stream>>>(col, deg);
  k_dis<<<(NP + 255) / 256, 256, 0, stream>>>(deg, dis);
  k_scan1<<<98, 1024, 0, stream>>>(deg, rowptr, bsum);
  k_scan2<<<1, 128, 0, stream>>>(bsum, bsum2);
  k_scan3<<<98, 1024, 0, stream>>>(rowptr, bsum2);
  k_fill<<<(NE + 255) / 256, 256, 0, stream>>>(row, col, dis, rowptr, cnt, csr_src, csr_w);

  // weight conversions (W_tag[g] is [4][128][128] == [512][128] k-major: matches cat order)
  k_wconv<<<(512 * CC + 255) / 256, 256, 0, stream>>>(W_tag,                 WpT0, 512);
  k_wconv<<<(512 * CC + 255) / 256, 256, 0, stream>>>(W_tag + 512 * CC,      WpT1, 512);
  k_wconv<<<(CC * CC + 255) / 256, 256, 0, stream>>>(W_mlp,                  WpM0, 128);
  k_wconv<<<(CC * CC + 255) / 256, 256, 0, stream>>>(W_mlp + CC * CC,        WpM1, 128);

  k_lin0<<<NP * CC / 256, 256, 0, stream>>>(x, W0, b0, hA);

  const int GB = NP / 128;             // 782 gemm blocks
  const int PB = NP * 64 / 256;        // prop blocks (4 waves each)

  _Float16* hc = hA;
  _Float16* hn = hB;
  const _Float16* WpT[2] = {WpT0, WpT1};
  for (int g = 0; g < 2; ++g) {
    k_prop<<<PB, 256, 0, stream>>>(rowptr, deg, csr_src, csr_w, hc, x1);
    k_prop<<<PB, 256, 0, stream>>>(rowptr, deg, csr_src, csr_w, x1, x2);
    k_prop<<<PB, 256, 0, stream>>>(rowptr, deg, csr_src, csr_w, x2, x3);
    k_mm<4, true><<<GB, 256, 0, stream>>>(hc, x1, x2, x3, WpT[g], b_tag + (size_t)g * CC, hn);
    _Float16* tmp = hc; hc = hn; hn = tmp;
  }

  k_mm<1, true><<<GB, 256, 0, stream>>>(hc, nullptr, nullptr, nullptr, WpM0, b_mlp, hn);
  { _Float16* tmp = hc; hc = hn; hn = tmp; }
  k_mm<1, true><<<GB, 256, 0, stream>>>(hc, nullptr, nullptr, nullptr, WpM1, b_mlp + CC, hn);
  { _Float16* tmp = hc; hc = hn; hn = tmp; }

  k_head<<<(NN * 64) / 256, 256, 0, stream>>>(hc, W1, b1, (float*)d_out);
}

// Round 9
// 411.711 us; speedup vs baseline: 2.8832x; 1.1879x over previous
//
#include <hip/hip_runtime.h>

#define NN 100000   // real nodes
#define NP 100096   // padded to 782*128
#define NE 600000   // edges
#define CC 128      // channels

typedef __attribute__((ext_vector_type(4))) float f32x4;
typedef _Float16 h8 __attribute__((ext_vector_type(8)));
typedef _Float16 h2 __attribute__((ext_vector_type(2)));

// ---------------- graph preprocessing ----------------

__global__ void k_deg(const int* __restrict__ col, int* __restrict__ deg) {
  int e = blockIdx.x * 256 + threadIdx.x;
  if (e < NE) atomicAdd(&deg[col[e]], 1);
}

__global__ void k_dis(const int* __restrict__ deg, float* __restrict__ dis) {
  int n = blockIdx.x * 256 + threadIdx.x;
  if (n >= NP) return;
  int d = (n < NN) ? deg[n] : 0;
  dis[n] = (d > 0) ? rsqrtf((float)d) : 0.0f;
}

__global__ void k_scan1(const int* __restrict__ deg, int* __restrict__ rowptr,
                        int* __restrict__ bsum) {
  __shared__ int s[1024];
  int t = threadIdx.x;
  int i = blockIdx.x * 1024 + t;
  int v = (i < NN) ? deg[i] : 0;
  s[t] = v;
  __syncthreads();
  #pragma unroll
  for (int off = 1; off < 1024; off <<= 1) {
    int tv = (t >= off) ? s[t - off] : 0;
    __syncthreads();
    s[t] += tv;
    __syncthreads();
  }
  if (i < NN) rowptr[i] = s[t] - v;           // exclusive
  if (t == 1023) bsum[blockIdx.x] = s[1023];
}

__global__ void k_scan2(const int* __restrict__ bsum, int* __restrict__ bsum2) {
  __shared__ int s[128];
  int t = threadIdx.x;
  int v = (t < 98) ? bsum[t] : 0;
  s[t] = v;
  __syncthreads();
  #pragma unroll
  for (int off = 1; off < 128; off <<= 1) {
    int tv = (t >= off) ? s[t - off] : 0;
    __syncthreads();
    s[t] += tv;
    __syncthreads();
  }
  bsum2[t] = s[t] - v;                        // exclusive
}

__global__ void k_scan3(int* __restrict__ rowptr, const int* __restrict__ bsum2) {
  int i = blockIdx.x * 1024 + threadIdx.x;
  if (i < NN) rowptr[i] += bsum2[blockIdx.x];
}

// packed CSR entry: {src_node*CC, float_bits(norm_w)} -> one 8B load per edge
__global__ void k_fill(const int* __restrict__ row, const int* __restrict__ col,
                       const float* __restrict__ dis, const int* __restrict__ rowptr,
                       int* __restrict__ cnt, int2* __restrict__ csr) {
  int e = blockIdx.x * 256 + threadIdx.x;
  if (e >= NE) return;
  int c = col[e], r = row[e];
  int pos = rowptr[c] + atomicAdd(&cnt[c], 1);
  int2 v;
  v.x = r * CC;
  v.y = __float_as_int(dis[r] * dis[c]);
  csr[pos] = v;
}

// ---------------- lin0: h = relu(x @ W0 + b0), x is [N,6], out fp16 ----------------

__global__ void k_lin0(const float* __restrict__ x, const float* __restrict__ W0,
                       const float* __restrict__ b0, _Float16* __restrict__ h) {
  int idx = blockIdx.x * 256 + threadIdx.x;   // n*128 + c
  int n = idx >> 7, c = idx & 127;
  if (n >= NP) return;
  float v = 0.0f;
  if (n < NN) {
    v = b0[c];
    #pragma unroll
    for (int f = 0; f < 6; ++f) v = fmaf(x[n * 6 + f], W0[f * CC + c], v);
    v = fmaxf(v, 0.0f);
  }
  h[idx] = (_Float16)v;
}

// ---------------- W conversion: fp32 [K][128] -> fp16 MFMA-B-permuted ----------------
// dst[((kb*8+nb)*64+l)*8+e] = src[(kb*32+(l>>4)*8+e)*128 + nb*16+(l&15)]

__global__ void k_wconv(const float* __restrict__ src, _Float16* __restrict__ dst, int K) {
  int tid = blockIdx.x * 256 + threadIdx.x;
  if (tid >= K * 128) return;
  int e = tid & 7, l = (tid >> 3) & 63, nb = (tid >> 9) & 7, kb = tid >> 12;
  int k = kb * 32 + (l >> 4) * 8 + e;
  int c = nb * 16 + (l & 15);
  dst[tid] = (_Float16)src[k * 128 + c];
}

// ---------------- propagation: coalesced edge prefetch + shfl broadcast ----------------
// one wave per node; lanes 0..d-1 hold edge (idx,w); all gathers issued with no
// index-load in the dependent chain. lane owns 2 channels (4B gather/lane).

__global__ void k_prop(const int* __restrict__ rowptr, const int* __restrict__ deg,
                       const int2* __restrict__ csr,
                       const _Float16* __restrict__ xin, _Float16* __restrict__ xout) {
  int gid = blockIdx.x * 256 + threadIdx.x;
  int wid = gid >> 6;            // node
  int lane = gid & 63;
  if (wid >= NP) return;
  float a0 = 0.0f, a1 = 0.0f;
  if (wid < NN) {
    int start = rowptr[wid], d = deg[wid];
    int2 ew; ew.x = 0; ew.y = 0;
    if (lane < d) ew = csr[start + lane];
    int nd = d < 64 ? d : 64;
    int nd4 = (nd + 3) & ~3;                  // pad with zero-weight edges (node 0, hot)
    for (int j = 0; j < nd4; j += 4) {
      #pragma unroll
      for (int u = 0; u < 4; ++u) {
        int off = __shfl(ew.x, j + u);
        float w = __uint_as_float(__shfl(ew.y, j + u));
        h2 v = *reinterpret_cast<const h2*>(&xin[off + lane * 2]);
        a0 += w * (float)v[0];
        a1 += w * (float)v[1];
      }
    }
    if (d > 64) {                             // rare tail
      for (int j = start + 64; j < start + d; ++j) {
        int2 e2 = csr[j];
        float w = __uint_as_float(e2.y);
        h2 v = *reinterpret_cast<const h2*>(&xin[e2.x + lane * 2]);
        a0 += w * (float)v[0];
        a1 += w * (float)v[1];
      }
    }
  }
  h2 o; o[0] = (_Float16)a0; o[1] = (_Float16)a1;
  *reinterpret_cast<h2*>(&xout[wid * CC + lane * 2]) = o;
}

// ---------------- MFMA GEMM: Y = relu?(cat(X0..X{KB-1}) @ Wp + bias) ----------------
// 4 waves, 128x128 tile. A staged via global_load_lds(16B) with source-pre-swizzled
// XOR (chunk ^= row&7) -> conflict-free ds_read_b128 fragments. B from permuted Wp.

template<int KB, bool BR>
__global__ __launch_bounds__(256) void k_mm(const _Float16* __restrict__ X0,
                                            const _Float16* __restrict__ X1,
                                            const _Float16* __restrict__ X2,
                                            const _Float16* __restrict__ X3,
                                            const _Float16* __restrict__ Wp,
                                            const float* __restrict__ bias,
                                            _Float16* __restrict__ Y) {
  __shared__ _Float16 lds[128 * 128];         // 32 KB
  int t = threadIdx.x;
  int w = t >> 6, l = t & 63;
  int lr = l & 15, lk = l >> 4;
  int m0w = (w & 1) * 64;
  int nb0 = (w >> 1) * 4;
  long row0 = (long)blockIdx.x * 128;
  const _Float16* Xs[4] = {X0, X1, X2, X3};

  f32x4 acc[4][4];
  #pragma unroll
  for (int m = 0; m < 4; ++m)
    #pragma unroll
    for (int n = 0; n < 4; ++n) acc[m][n] = (f32x4){0.f, 0.f, 0.f, 0.f};

  #pragma unroll
  for (int xi = 0; xi < KB; ++xi) {
    const _Float16* __restrict__ xb = Xs[xi];
    // stage [128][128] fp16 tile; LDS linear, global source pre-swizzled
    #pragma unroll
    for (int i = 0; i < 8; ++i) {
      int li = i * 256 + t;                   // 16B-granule index 0..2047
      int r = li >> 4, ck = li & 15;
      int cs = ck ^ (r & 7);
      const _Float16* src = xb + (size_t)(row0 + r) * CC + cs * 8;
      _Float16* dst = lds + ((size_t)i * 2048 + (size_t)(t & 192) * 8);  // wave-uniform base
      __builtin_amdgcn_global_load_lds((const __attribute__((address_space(1))) void*)src,
                                       (__attribute__((address_space(3))) void*)dst,
                                       16, 0, 0);
    }
    __syncthreads();                          // drains vmcnt before LDS reads

    #pragma unroll
    for (int kk = 0; kk < 4; ++kk) {
      int kb = xi * 4 + kk;
      h8 a[4], b[4];
      #pragma unroll
      for (int m = 0; m < 4; ++m) {
        int R = m0w + m * 16 + lr;
        a[m] = *reinterpret_cast<const h8*>(&lds[R * 128 + (((kk * 4 + lk) ^ (lr & 7)) << 3)]);
      }
      #pragma unroll
      for (int n = 0; n < 4; ++n)
        b[n] = *reinterpret_cast<const h8*>(&Wp[((size_t)(kb * 8 + nb0 + n) * 64 + l) * 8]);
      #pragma unroll
      for (int m = 0; m < 4; ++m)
        #pragma unroll
        for (int n = 0; n < 4; ++n)
          acc[m][n] = __builtin_amdgcn_mfma_f32_16x16x32_f16(a[m], b[n], acc[m][n], 0, 0, 0);
    }
    __syncthreads();                          // before next stage overwrites
  }

  // C/D layout: col = lane&15, row = (lane>>4)*4 + reg
  int r0 = m0w + lk * 4;
  long rb = row0 + r0;
  #pragma unroll
  for (int m = 0; m < 4; ++m) {
    #pragma unroll
    for (int n = 0; n < 4; ++n) {
      int c = (nb0 + n) * 16 + lr;
      float bv = BR ? bias[c] : 0.0f;
      #pragma unroll
      for (int q = 0; q < 4; ++q) {
        float v = acc[m][n][q] + bv;
        if (BR) v = fmaxf(v, 0.0f);
        Y[(rb + m * 16 + q) * CC + c] = (_Float16)v;
      }
    }
  }
}

// ---------------- head: out = relu(h @ W1 + b1), one wave per node ----------------

__global__ void k_head(const _Float16* __restrict__ h, const float* __restrict__ W1,
                       const float* __restrict__ b1, float* __restrict__ out) {
  int gid = blockIdx.x * 256 + threadIdx.x;
  int wid = gid >> 6, lane = gid & 63;
  if (wid >= NN) return;
  const _Float16* hp = &h[wid * CC];
  float v = (float)hp[lane] * W1[lane] + (float)hp[lane + 64] * W1[lane + 64];
  #pragma unroll
  for (int o = 32; o > 0; o >>= 1) v += __shfl_down(v, o);
  if (lane == 0) out[wid] = fmaxf(v + b1[0], 0.0f);
}

// ---------------- launch ----------------

extern "C" void kernel_launch(void* const* d_in, const int* in_sizes, int n_in,
                              void* d_out, int out_size, void* d_ws, size_t ws_size,
                              hipStream_t stream) {
  const float* x     = (const float*)d_in[0];
  const int*   ei    = (const int*)d_in[1];
  const float* W0    = (const float*)d_in[2];
  const float* b0    = (const float*)d_in[3];
  const float* W_tag = (const float*)d_in[4];
  const float* b_tag = (const float*)d_in[5];
  const float* W_mlp = (const float*)d_in[6];
  const float* b_mlp = (const float*)d_in[7];
  const float* W1    = (const float*)d_in[8];
  const float* b1    = (const float*)d_in[9];
  const int* row = ei;          // edge_index[0] = source
  const int* col = ei + NE;     // edge_index[1] = target

  char* p = (char*)d_ws;
  auto carve = [&](size_t bytes) { void* r = (void*)p; p += (bytes + 255) & ~(size_t)255; return r; };
  _Float16* hA   = (_Float16*)carve((size_t)NP * CC * 2);
  _Float16* hB   = (_Float16*)carve((size_t)NP * CC * 2);
  _Float16* x1   = (_Float16*)carve((size_t)NP * CC * 2);
  _Float16* x2   = (_Float16*)carve((size_t)NP * CC * 2);
  _Float16* x3   = (_Float16*)carve((size_t)NP * CC * 2);
  _Float16* WpT0 = (_Float16*)carve((size_t)512 * CC * 2);
  _Float16* WpT1 = (_Float16*)carve((size_t)512 * CC * 2);
  _Float16* WpM0 = (_Float16*)carve((size_t)CC * CC * 2);
  _Float16* WpM1 = (_Float16*)carve((size_t)CC * CC * 2);
  float* dis     = (float*)carve((size_t)NP * 4);
  int*   deg     = (int*)carve((size_t)NP * 4);
  int*   rowptr  = (int*)carve((size_t)NN * 4);
  int*   cnt     = (int*)carve((size_t)NN * 4);
  int*   bsum    = (int*)carve(512);
  int*   bsum2   = (int*)carve(512);
  int2*  csr     = (int2*)carve((size_t)NE * 8);

  hipMemsetAsync(deg, 0, (size_t)NP * 4, stream);
  hipMemsetAsync(cnt, 0, (size_t)NN * 4, stream);

  k_deg<<<(NE + 255) / 256, 256, 0, stream>>>(col, deg);
  k_dis<<<(NP + 255) / 256, 256, 0, stream>>>(deg, dis);
  k_scan1<<<98, 1024, 0, stream>>>(deg, rowptr, bsum);
  k_scan2<<<1, 128, 0, stream>>>(bsum, bsum2);
  k_scan3<<<98, 1024, 0, stream>>>(rowptr, bsum2);
  k_fill<<<(NE + 255) / 256, 256, 0, stream>>>(row, col, dis, rowptr, cnt, csr);

  // weight conversions (W_tag[g] is [4][128][128] == [512][128] k-major: matches cat order)
  k_wconv<<<(512 * CC + 255) / 256, 256, 0, stream>>>(W_tag,            WpT0, 512);
  k_wconv<<<(512 * CC + 255) / 256, 256, 0, stream>>>(W_tag + 512 * CC, WpT1, 512);
  k_wconv<<<(CC * CC + 255) / 256, 256, 0, stream>>>(W_mlp,             WpM0, 128);
  k_wconv<<<(CC * CC + 255) / 256, 256, 0, stream>>>(W_mlp + CC * CC,   WpM1, 128);

  k_lin0<<<NP * CC / 256, 256, 0, stream>>>(x, W0, b0, hA);

  const int GB = NP / 128;             // 782 gemm blocks
  const int PB = NP * 64 / 256;        // prop blocks (4 waves each)

  _Float16* hc = hA;
  _Float16* hn = hB;
  const _Float16* WpT[2] = {WpT0, WpT1};
  for (int g = 0; g < 2; ++g) {
    k_prop<<<PB, 256, 0, stream>>>(rowptr, deg, csr, hc, x1);
    k_prop<<<PB, 256, 0, stream>>>(rowptr, deg, csr, x1, x2);
    k_prop<<<PB, 256, 0, stream>>>(rowptr, deg, csr, x2, x3);
    k_mm<4, true><<<GB, 256, 0, stream>>>(hc, x1, x2, x3, WpT[g], b_tag + (size_t)g * CC, hn);
    _Float16* tmp = hc; hc = hn; hn = tmp;
  }

  k_mm<1, true><<<GB, 256, 0, stream>>>(hc, nullptr, nullptr, nullptr, WpM0, b_mlp, hn);
  { _Float16* tmp = hc; hc = hn; hn = tmp; }
  k_mm<1, true><<<GB, 256, 0, stream>>>(hc, nullptr, nullptr, nullptr, WpM1, b_mlp + CC, hn);
  { _Float16* tmp = hc; hc = hn; hn = tmp; }

  k_head<<<(NN * 64) / 256, 256, 0, stream>>>(hc, W1, b1, (float*)d_out);
}

// Round 10
// 402.105 us; speedup vs baseline: 2.9520x; 1.0239x over previous
//
#include <hip/hip_runtime.h>

#define NN 100000   // real nodes
#define NP 100096   // padded to 782*128
#define NE 600000   // edges
#define CC 128      // channels

typedef __attribute__((ext_vector_type(4))) float f32x4;
typedef _Float16 h8 __attribute__((ext_vector_type(8)));
typedef _Float16 h2 __attribute__((ext_vector_type(2)));

// ---------------- graph preprocessing ----------------

__global__ void k_deg(const int* __restrict__ col, int* __restrict__ deg) {
  int e = blockIdx.x * 256 + threadIdx.x;
  if (e < NE) atomicAdd(&deg[col[e]], 1);
}

__global__ void k_dis(const int* __restrict__ deg, float* __restrict__ dis) {
  int n = blockIdx.x * 256 + threadIdx.x;
  if (n >= NP) return;
  int d = (n < NN) ? deg[n] : 0;
  dis[n] = (d > 0) ? rsqrtf((float)d) : 0.0f;
}

__global__ void k_scan1(const int* __restrict__ deg, int* __restrict__ rowptr,
                        int* __restrict__ bsum) {
  __shared__ int s[1024];
  int t = threadIdx.x;
  int i = blockIdx.x * 1024 + t;
  int v = (i < NN) ? deg[i] : 0;
  s[t] = v;
  __syncthreads();
  #pragma unroll
  for (int off = 1; off < 1024; off <<= 1) {
    int tv = (t >= off) ? s[t - off] : 0;
    __syncthreads();
    s[t] += tv;
    __syncthreads();
  }
  if (i < NN) rowptr[i] = s[t] - v;           // exclusive
  if (t == 1023) bsum[blockIdx.x] = s[1023];
}

__global__ void k_scan2(const int* __restrict__ bsum, int* __restrict__ bsum2) {
  __shared__ int s[128];
  int t = threadIdx.x;
  int v = (t < 98) ? bsum[t] : 0;
  s[t] = v;
  __syncthreads();
  #pragma unroll
  for (int off = 1; off < 128; off <<= 1) {
    int tv = (t >= off) ? s[t - off] : 0;
    __syncthreads();
    s[t] += tv;
    __syncthreads();
  }
  bsum2[t] = s[t] - v;                        // exclusive
}

__global__ void k_scan3(int* __restrict__ rowptr, const int* __restrict__ bsum2) {
  int i = blockIdx.x * 1024 + threadIdx.x;
  if (i < NN) rowptr[i] += bsum2[blockIdx.x];
}

// tail: rowptr[NN .. NP+7] = NE (empty ranges for padded nodes)
__global__ void k_rptail(int* __restrict__ rowptr) {
  int i = NN + blockIdx.x * 256 + threadIdx.x;
  if (i < NP + 8) rowptr[i] = NE;
}

// packed CSR entry: {src_node*CC, float_bits(norm_w)} -> one 8B load per edge
__global__ void k_fill(const int* __restrict__ row, const int* __restrict__ col,
                       const float* __restrict__ dis, const int* __restrict__ rowptr,
                       int* __restrict__ cnt, int2* __restrict__ csr) {
  int e = blockIdx.x * 256 + threadIdx.x;
  if (e >= NE) return;
  int c = col[e], r = row[e];
  int pos = rowptr[c] + atomicAdd(&cnt[c], 1);
  int2 v;
  v.x = r * CC;
  v.y = __float_as_int(dis[r] * dis[c]);
  csr[pos] = v;
}

// ---------------- lin0: h = relu(x @ W0 + b0), x is [N,6], out fp16 ----------------

__global__ void k_lin0(const float* __restrict__ x, const float* __restrict__ W0,
                       const float* __restrict__ b0, _Float16* __restrict__ h) {
  int idx = blockIdx.x * 256 + threadIdx.x;   // n*128 + c
  int n = idx >> 7, c = idx & 127;
  if (n >= NP) return;
  float v = 0.0f;
  if (n < NN) {
    v = b0[c];
    #pragma unroll
    for (int f = 0; f < 6; ++f) v = fmaf(x[n * 6 + f], W0[f * CC + c], v);
    v = fmaxf(v, 0.0f);
  }
  h[idx] = (_Float16)v;
}

// ---------------- W conversion: fp32 [K][128] -> fp16 MFMA-B-permuted ----------------
// dst[((kb*8+nb)*64+l)*8+e] = src[(kb*32+(l>>4)*8+e)*128 + nb*16+(l&15)]

__global__ void k_wconv(const float* __restrict__ src, _Float16* __restrict__ dst, int K) {
  int tid = blockIdx.x * 256 + threadIdx.x;
  if (tid >= K * 128) return;
  int e = tid & 7, l = (tid >> 3) & 63, nb = (tid >> 9) & 7, kb = tid >> 12;
  int k = kb * 32 + (l >> 4) * 8 + e;
  int c = nb * 16 + (l & 15);
  dst[tid] = (_Float16)src[k * 128 + c];
}

// ---------------- propagation: 4 nodes/wave, contiguous CSR, 8-deep gather MLP ----
// lanes prefetch the 4 nodes' packed edges (contiguous in CSR); per edge, shfl
// broadcasts (off,w,node-slot); branchless 4-way select accumulates. lane owns 2 ch.

__global__ __launch_bounds__(256) void k_prop(const int* __restrict__ rowptr,
                                              const int2* __restrict__ csr,
                                              const _Float16* __restrict__ xin,
                                              _Float16* __restrict__ xout) {
  int gid = blockIdx.x * 256 + threadIdx.x;
  int wv = gid >> 6;             // wave -> nodes 4*wv .. 4*wv+3
  int lane = gid & 63;
  int n0 = wv * 4;
  if (n0 >= NP) return;
  int b0 = rowptr[n0], b1 = rowptr[n0 + 1], b2 = rowptr[n0 + 2],
      b3 = rowptr[n0 + 3], b4 = rowptr[n0 + 4];
  int e4 = b4 - b0;

  int2 ew; ew.x = 0; ew.y = 0;   // w=0 padding: contributes nothing, gathers node 0
  int gl = 0;
  if (lane < e4) {
    int pos = b0 + lane;
    ew = csr[pos];
    gl = (pos >= b1) + (pos >= b2) + (pos >= b3);
  }

  float a00 = 0, a01 = 0, a10 = 0, a11 = 0, a20 = 0, a21 = 0, a30 = 0, a31 = 0;
  int nb = e4 < 64 ? e4 : 64;
  for (int j = 0; j < nb; j += 8) {
    #pragma unroll
    for (int u = 0; u < 8; ++u) {
      int off = __shfl(ew.x, j + u);
      float w = __uint_as_float(__shfl(ew.y, j + u));
      int gg = __shfl(gl, j + u);
      h2 v = *reinterpret_cast<const h2*>(&xin[off + lane * 2]);
      float v0 = (float)v[0], v1 = (float)v[1];
      float w0 = (gg == 0) ? w : 0.0f;
      float w1 = (gg == 1) ? w : 0.0f;
      float w2 = (gg == 2) ? w : 0.0f;
      float w3 = (gg == 3) ? w : 0.0f;
      a00 += w0 * v0; a01 += w0 * v1;
      a10 += w1 * v0; a11 += w1 * v1;
      a20 += w2 * v0; a21 += w2 * v1;
      a30 += w3 * v0; a31 += w3 * v1;
    }
  }
  for (int j = 64; j < e4; ++j) {              // astronomically rare tail
    int pos = b0 + j;
    int2 e2 = csr[pos];
    float w = __uint_as_float(e2.y);
    int gg = (pos >= b1) + (pos >= b2) + (pos >= b3);
    h2 v = *reinterpret_cast<const h2*>(&xin[e2.x + lane * 2]);
    float v0 = (float)v[0], v1 = (float)v[1];
    float w0 = (gg == 0) ? w : 0.0f;
    float w1 = (gg == 1) ? w : 0.0f;
    float w2 = (gg == 2) ? w : 0.0f;
    float w3 = (gg == 3) ? w : 0.0f;
    a00 += w0 * v0; a01 += w0 * v1;
    a10 += w1 * v0; a11 += w1 * v1;
    a20 += w2 * v0; a21 += w2 * v1;
    a30 += w3 * v0; a31 += w3 * v1;
  }

  h2 o;
  o[0] = (_Float16)a00; o[1] = (_Float16)a01;
  *reinterpret_cast<h2*>(&xout[(size_t)(n0 + 0) * CC + lane * 2]) = o;
  o[0] = (_Float16)a10; o[1] = (_Float16)a11;
  *reinterpret_cast<h2*>(&xout[(size_t)(n0 + 1) * CC + lane * 2]) = o;
  o[0] = (_Float16)a20; o[1] = (_Float16)a21;
  *reinterpret_cast<h2*>(&xout[(size_t)(n0 + 2) * CC + lane * 2]) = o;
  o[0] = (_Float16)a30; o[1] = (_Float16)a31;
  *reinterpret_cast<h2*>(&xout[(size_t)(n0 + 3) * CC + lane * 2]) = o;
}

// ---------------- MFMA GEMM: Y = relu?(cat(X0..X{KB-1}) @ Wp + bias) ----------------
// 4 waves, 128x128 tile. A staged via global_load_lds(16B) with source-pre-swizzled
// XOR (chunk ^= row&7) -> conflict-free ds_read_b128 fragments. B from permuted Wp.

template<int KB, bool BR>
__global__ __launch_bounds__(256) void k_mm(const _Float16* __restrict__ X0,
                                            const _Float16* __restrict__ X1,
                                            const _Float16* __restrict__ X2,
                                            const _Float16* __restrict__ X3,
                                            const _Float16* __restrict__ Wp,
                                            const float* __restrict__ bias,
                                            _Float16* __restrict__ Y) {
  __shared__ _Float16 lds[128 * 128];         // 32 KB
  int t = threadIdx.x;
  int w = t >> 6, l = t & 63;
  int lr = l & 15, lk = l >> 4;
  int m0w = (w & 1) * 64;
  int nb0 = (w >> 1) * 4;
  long row0 = (long)blockIdx.x * 128;
  const _Float16* Xs[4] = {X0, X1, X2, X3};

  f32x4 acc[4][4];
  #pragma unroll
  for (int m = 0; m < 4; ++m)
    #pragma unroll
    for (int n = 0; n < 4; ++n) acc[m][n] = (f32x4){0.f, 0.f, 0.f, 0.f};

  #pragma unroll
  for (int xi = 0; xi < KB; ++xi) {
    const _Float16* __restrict__ xb = Xs[xi];
    // stage [128][128] fp16 tile; LDS linear, global source pre-swizzled
    #pragma unroll
    for (int i = 0; i < 8; ++i) {
      int li = i * 256 + t;                   // 16B-granule index 0..2047
      int r = li >> 4, ck = li & 15;
      int cs = ck ^ (r & 7);
      const _Float16* src = xb + (size_t)(row0 + r) * CC + cs * 8;
      _Float16* dst = lds + ((size_t)i * 2048 + (size_t)(t & 192) * 8);  // wave-uniform base
      __builtin_amdgcn_global_load_lds((const __attribute__((address_space(1))) void*)src,
                                       (__attribute__((address_space(3))) void*)dst,
                                       16, 0, 0);
    }
    __syncthreads();                          // drains vmcnt before LDS reads

    #pragma unroll
    for (int kk = 0; kk < 4; ++kk) {
      int kb = xi * 4 + kk;
      h8 a[4], b[4];
      #pragma unroll
      for (int m = 0; m < 4; ++m) {
        int R = m0w + m * 16 + lr;
        a[m] = *reinterpret_cast<const h8*>(&lds[R * 128 + (((kk * 4 + lk) ^ (lr & 7)) << 3)]);
      }
      #pragma unroll
      for (int n = 0; n < 4; ++n)
        b[n] = *reinterpret_cast<const h8*>(&Wp[((size_t)(kb * 8 + nb0 + n) * 64 + l) * 8]);
      #pragma unroll
      for (int m = 0; m < 4; ++m)
        #pragma unroll
        for (int n = 0; n < 4; ++n)
          acc[m][n] = __builtin_amdgcn_mfma_f32_16x16x32_f16(a[m], b[n], acc[m][n], 0, 0, 0);
    }
    __syncthreads();                          // before next stage overwrites
  }

  // C/D layout: col = lane&15, row = (lane>>4)*4 + reg
  int r0 = m0w + lk * 4;
  long rb = row0 + r0;
  #pragma unroll
  for (int m = 0; m < 4; ++m) {
    #pragma unroll
    for (int n = 0; n < 4; ++n) {
      int c = (nb0 + n) * 16 + lr;
      float bv = BR ? bias[c] : 0.0f;
      #pragma unroll
      for (int q = 0; q < 4; ++q) {
        float v = acc[m][n][q] + bv;
        if (BR) v = fmaxf(v, 0.0f);
        Y[(rb + m * 16 + q) * CC + c] = (_Float16)v;
      }
    }
  }
}

// ---------------- head: out = relu(h @ W1 + b1), one wave per node ----------------

__global__ void k_head(const _Float16* __restrict__ h, const float* __restrict__ W1,
                       const float* __restrict__ b1, float* __restrict__ out) {
  int gid = blockIdx.x * 256 + threadIdx.x;
  int wid = gid >> 6, lane = gid & 63;
  if (wid >= NN) return;
  const _Float16* hp = &h[wid * CC];
  float v = (float)hp[lane] * W1[lane] + (float)hp[lane + 64] * W1[lane + 64];
  #pragma unroll
  for (int o = 32; o > 0; o >>= 1) v += __shfl_down(v, o);
  if (lane == 0) out[wid] = fmaxf(v + b1[0], 0.0f);
}

// ---------------- launch ----------------

extern "C" void kernel_launch(void* const* d_in, const int* in_sizes, int n_in,
                              void* d_out, int out_size, void* d_ws, size_t ws_size,
                              hipStream_t stream) {
  const float* x     = (const float*)d_in[0];
  const int*   ei    = (const int*)d_in[1];
  const float* W0    = (const float*)d_in[2];
  const float* b0    = (const float*)d_in[3];
  const float* W_tag = (const float*)d_in[4];
  const float* b_tag = (const float*)d_in[5];
  const float* W_mlp = (const float*)d_in[6];
  const float* b_mlp = (const float*)d_in[7];
  const float* W1    = (const float*)d_in[8];
  const float* b1    = (const float*)d_in[9];
  const int* row = ei;          // edge_index[0] = source
  const int* col = ei + NE;     // edge_index[1] = target

  char* p = (char*)d_ws;
  auto carve = [&](size_t bytes) { void* r = (void*)p; p += (bytes + 255) & ~(size_t)255; return r; };
  _Float16* hA   = (_Float16*)carve((size_t)NP * CC * 2);
  _Float16* hB   = (_Float16*)carve((size_t)NP * CC * 2);
  _Float16* x1   = (_Float16*)carve((size_t)NP * CC * 2);
  _Float16* x2   = (_Float16*)carve((size_t)NP * CC * 2);
  _Float16* x3   = (_Float16*)carve((size_t)NP * CC * 2);
  _Float16* WpT0 = (_Float16*)carve((size_t)512 * CC * 2);
  _Float16* WpT1 = (_Float16*)carve((size_t)512 * CC * 2);
  _Float16* WpM0 = (_Float16*)carve((size_t)CC * CC * 2);
  _Float16* WpM1 = (_Float16*)carve((size_t)CC * CC * 2);
  float* dis     = (float*)carve((size_t)NP * 4);
  int*   deg     = (int*)carve((size_t)NP * 4);
  int*   rowptr  = (int*)carve((size_t)(NP + 8) * 4);
  int*   cnt     = (int*)carve((size_t)NN * 4);
  int*   bsum    = (int*)carve(512);
  int*   bsum2   = (int*)carve(512);
  int2*  csr     = (int2*)carve((size_t)NE * 8);

  hipMemsetAsync(deg, 0, (size_t)NP * 4, stream);
  hipMemsetAsync(cnt, 0, (size_t)NN * 4, stream);

  k_deg<<<(NE + 255) / 256, 256, 0, stream>>>(col, deg);
  k_dis<<<(NP + 255) / 256, 256, 0, stream>>>(deg, dis);
  k_scan1<<<98, 1024, 0, stream>>>(deg, rowptr, bsum);
  k_scan2<<<1, 128, 0, stream>>>(bsum, bsum2);
  k_scan3<<<98, 1024, 0, stream>>>(rowptr, bsum2);
  k_rptail<<<1, 256, 0, stream>>>(rowptr);
  k_fill<<<(NE + 255) / 256, 256, 0, stream>>>(row, col, dis, rowptr, cnt, csr);

  // weight conversions (W_tag[g] is [4][128][128] == [512][128] k-major: matches cat order)
  k_wconv<<<(512 * CC + 255) / 256, 256, 0, stream>>>(W_tag,            WpT0, 512);
  k_wconv<<<(512 * CC + 255) / 256, 256, 0, stream>>>(W_tag + 512 * CC, WpT1, 512);
  k_wconv<<<(CC * CC + 255) / 256, 256, 0, stream>>>(W_mlp,             WpM0, 128);
  k_wconv<<<(CC * CC + 255) / 256, 256, 0, stream>>>(W_mlp + CC * CC,   WpM1, 128);

  k_lin0<<<NP * CC / 256, 256, 0, stream>>>(x, W0, b0, hA);

  const int GB = NP / 128;             // 782 gemm blocks
  const int PB = (NP / 4) * 64 / 256;  // prop blocks: 4 nodes/wave, 4 waves/block

  _Float16* hc = hA;
  _Float16* hn = hB;
  const _Float16* WpT[2] = {WpT0, WpT1};
  for (int g = 0; g < 2; ++g) {
    k_prop<<<PB, 256, 0, stream>>>(rowptr, csr, hc, x1);
    k_prop<<<PB, 256, 0, stream>>>(rowptr, csr, x1, x2);
    k_prop<<<PB, 256, 0, stream>>>(rowptr, csr, x2, x3);
    k_mm<4, true><<<GB, 256, 0, stream>>>(hc, x1, x2, x3, WpT[g], b_tag + (size_t)g * CC, hn);
    _Float16* tmp = hc; hc = hn; hn = tmp;
  }

  k_mm<1, true><<<GB, 256, 0, stream>>>(hc, nullptr, nullptr, nullptr, WpM0, b_mlp, hn);
  { _Float16* tmp = hc; hc = hn; hn = tmp; }
  k_mm<1, true><<<GB, 256, 0, stream>>>(hc, nullptr, nullptr, nullptr, WpM1, b_mlp + CC, hn);
  { _Float16* tmp = hc; hc = hn; hn = tmp; }

  k_head<<<(NN * 64) / 256, 256, 0, stream>>>(hc, W1, b1, (float*)d_out);
}